// Round 3
// baseline (749.682 us; speedup 1.0000x reference)
//
#include <hip/hip_runtime.h>

typedef __bf16 bf16x8 __attribute__((ext_vector_type(8)));
typedef float f32x4 __attribute__((ext_vector_type(4)));

constexpr int NN = 50000;   // nodes
constexpr int NE = 800000;  // edges
constexpr int DIN = 256, DHID = 256, DOUT = 128;

__device__ __forceinline__ unsigned short f2bf(float f) {
  unsigned u = __float_as_uint(f);
  u += 0x7fffu + ((u >> 16) & 1u);  // RNE
  return (unsigned short)(u >> 16);
}
__device__ __forceinline__ float bf2f(unsigned short h) {
  return __uint_as_float(((unsigned)h) << 16);
}

// ---------------- CSR build ----------------

__global__ void hist_kernel(const int* __restrict__ e0, const int* __restrict__ e1,
                            int* __restrict__ counts) {
  int g = blockIdx.y;
  const int* dst = (g ? e1 : e0) + NE;  // edge_index row 1
  int* c = counts + g * NN;
  int i = blockIdx.x * blockDim.x + threadIdx.x;
  if (i < NE) atomicAdd(&c[dst[i]], 1);
}

// scan + dinv fused; one block per graph
__global__ void scan_kernel(const int* __restrict__ counts, int* __restrict__ rowptr,
                            int* __restrict__ cursor, float* __restrict__ dinv) {
  int g = blockIdx.x;
  const int* c = counts + g * NN;
  int* rp = rowptr + g * (NN + 1);
  int* cur = cursor + g * NN;
  float* dv = dinv + g * NN;
  int t = threadIdx.x;
  constexpr int B = 1024;
  constexpr int CH = (NN + B - 1) / B;  // 49
  int b0 = t * CH, b1v = min(b0 + CH, NN);
  int tot = 0;
  for (int i = b0; i < b1v; i++) {
    int ci = c[i];
    dv[i] = rsqrtf((float)(ci + 1));  // +1 self-loop, deg>=1
    tot += ci;
  }
  __shared__ int sh[B];
  sh[t] = tot;
  __syncthreads();
  for (int off = 1; off < B; off <<= 1) {
    int v = (t >= off) ? sh[t - off] : 0;
    __syncthreads();
    sh[t] += v;
    __syncthreads();
  }
  int run = (t == 0) ? 0 : sh[t - 1];  // exclusive base
  for (int i = b0; i < b1v; i++) {
    rp[i] = run; cur[i] = run;
    run += c[i];
  }
  if (t == B - 1) rp[NN] = sh[B - 1];
}

__global__ void scatter_kernel(const int* __restrict__ e0, const int* __restrict__ e1,
                               int* __restrict__ cursor, unsigned short* __restrict__ col) {
  int g = blockIdx.y;
  const int* e = g ? e1 : e0;
  int* cur = cursor + g * NN;
  unsigned short* cl = col + g * NE;
  int i = blockIdx.x * blockDim.x + threadIdx.x;
  if (i < NE) {
    int s = e[i], d = e[NE + i];
    int slot = atomicAdd(&cur[d], 1);
    cl[slot] = (unsigned short)s;
  }
}

// ---------------- Pack W into B-fragment order ----------------
// Wpack flat index: ((kb*NT + nt)*64 + lane)*8 + j  holds W[kb*32 + (lane>>4)*8 + j][nt*16 + (lane&15)]

__global__ void pack_kernel(const float* __restrict__ W1, const float* __restrict__ W2,
                            unsigned short* __restrict__ P1, unsigned short* __restrict__ P2) {
  int i = blockIdx.x * blockDim.x + threadIdx.x;
  constexpr int N1 = 8 * 16 * 64 * 8;  // 65536 (K=256, N=256)
  constexpr int N2 = 8 * 8 * 64 * 8;   // 32768 (K=256, N=128)
  if (i < N1) {
    int j = i & 7, lane = (i >> 3) & 63, grp = i >> 9;
    int nt = grp & 15, kb = grp >> 4;
    int k = kb * 32 + (lane >> 4) * 8 + j;
    int n = nt * 16 + (lane & 15);
    P1[i] = f2bf(W1[k * DHID + n]);
  } else if (i < N1 + N2) {
    int ii = i - N1;
    int j = ii & 7, lane = (ii >> 3) & 63, grp = ii >> 9;
    int nt = grp & 7, kb = grp >> 3;
    int k = kb * 32 + (lane >> 4) * 8 + j;
    int n = nt * 16 + (lane & 15);
    P2[ii] = f2bf(W2[k * DOUT + n]);
  }
}

// ---------------- MFMA matmul: C[M,N] = (A[M,256] @ W) * dinv[row] ----------------
// wave handles 16 rows x N cols; block = 4 waves = 64 rows.
// Rows are pre-scaled by dinv so aggregation is a plain sum (norm factored).

template <int N, bool AF32>
__global__ __launch_bounds__(256) void mm_kernel(
    const void* __restrict__ A0, const void* __restrict__ A1,
    const unsigned short* __restrict__ Wp, unsigned short* __restrict__ Cb,
    const float* __restrict__ dinv, long long gstride) {
  constexpr int NT = N / 16;
  constexpr int K = 256;
  int g = blockIdx.y;
  const void* A = g ? A1 : A0;
  unsigned short* C = Cb + (size_t)g * gstride;
  const float* dv = dinv + g * NN;
  int wave = threadIdx.x >> 6, lane = threadIdx.x & 63;
  int q = lane >> 4, lm = lane & 15;
  int m0 = blockIdx.x * 64 + wave * 16;
  int row = m0 + lm;
  int rowc = min(row, NN - 1);
  f32x4 acc[NT];
#pragma unroll
  for (int nt = 0; nt < NT; nt++) acc[nt] = (f32x4){0.f, 0.f, 0.f, 0.f};
#pragma unroll
  for (int kb = 0; kb < K / 32; kb++) {
    int kc = kb * 32 + q * 8;  // lane's contiguous k-chunk (A frag: k = quad*8+j)
    bf16x8 a;
    if constexpr (AF32) {
      const float* Af = (const float*)A + (size_t)rowc * K + kc;
      const float4 v0 = *(const float4*)Af;
      const float4 v1 = *(const float4*)(Af + 4);
      a[0] = (__bf16)v0.x; a[1] = (__bf16)v0.y; a[2] = (__bf16)v0.z; a[3] = (__bf16)v0.w;
      a[4] = (__bf16)v1.x; a[5] = (__bf16)v1.y; a[6] = (__bf16)v1.z; a[7] = (__bf16)v1.w;
    } else {
      const unsigned short* Ab = (const unsigned short*)A + (size_t)rowc * K + kc;
      a = *(const bf16x8*)Ab;
    }
#pragma unroll
    for (int nt = 0; nt < NT; nt++) {
      bf16x8 b = *(const bf16x8*)(Wp + (((size_t)kb * NT + nt) * 64 + lane) * 8);
      acc[nt] = __builtin_amdgcn_mfma_f32_16x16x32_bf16(a, b, acc[nt], 0, 0, 0);
    }
  }
  // C/D layout: col = lane&15, row = quad*4 + reg
  float dvr[4];
#pragma unroll
  for (int r = 0; r < 4; r++) dvr[r] = dv[min(m0 + q * 4 + r, NN - 1)];
#pragma unroll
  for (int nt = 0; nt < NT; nt++) {
#pragma unroll
    for (int r = 0; r < 4; r++) {
      int grow = m0 + q * 4 + r;
      if (grow < NN) C[(size_t)grow * N + nt * 16 + lm] = f2bf(acc[nt][r] * dvr[r]);
    }
  }
}

// ---------------- Aggregation (gather over CSR), fused scale+bias(+ReLU) ----------
// one wave per node; D=256: lane covers 4 cols. Rows pre-scaled by dinv[src], so
// inner loop is a pure gather-add; epilogue multiplies by dinv[node].
// Unroll 16/8/1 for memory-level parallelism.

__global__ __launch_bounds__(256) void agg1_kernel(
    const unsigned short* __restrict__ m1, unsigned short* __restrict__ a1,
    const int* __restrict__ rowptr, const unsigned short* __restrict__ col,
    const float* __restrict__ dinv, const float* __restrict__ b1) {
  int g = blockIdx.y;
  const unsigned short* H = m1 + (size_t)g * NN * DHID;
  unsigned short* O = a1 + (size_t)g * NN * DHID;
  const int* rp = rowptr + g * (NN + 1);
  const unsigned short* cl = col + (size_t)g * NE;
  const float* dv = dinv + g * NN;
  int node = blockIdx.x * 4 + (threadIdx.x >> 6);
  if (node >= NN) return;
  int lane = threadIdx.x & 63;
  ushort4 sv = *(const ushort4*)(H + (size_t)node * DHID + lane * 4);
  float a0 = bf2f(sv.x), a1v = bf2f(sv.y), a2 = bf2f(sv.z), a3 = bf2f(sv.w);
  int jb = rp[node], je = rp[node + 1];
  int j = jb;
  for (; j + 16 <= je; j += 16) {
    int s[16];
    ushort4 v[16];
#pragma unroll
    for (int u = 0; u < 16; u++) s[u] = cl[j + u];
#pragma unroll
    for (int u = 0; u < 16; u++) v[u] = *(const ushort4*)(H + (size_t)s[u] * DHID + lane * 4);
#pragma unroll
    for (int u = 0; u < 16; u++) {
      a0 += bf2f(v[u].x); a1v += bf2f(v[u].y);
      a2 += bf2f(v[u].z); a3 += bf2f(v[u].w);
    }
  }
  for (; j + 8 <= je; j += 8) {
    int s[8];
    ushort4 v[8];
#pragma unroll
    for (int u = 0; u < 8; u++) s[u] = cl[j + u];
#pragma unroll
    for (int u = 0; u < 8; u++) v[u] = *(const ushort4*)(H + (size_t)s[u] * DHID + lane * 4);
#pragma unroll
    for (int u = 0; u < 8; u++) {
      a0 += bf2f(v[u].x); a1v += bf2f(v[u].y);
      a2 += bf2f(v[u].z); a3 += bf2f(v[u].w);
    }
  }
  for (; j < je; j++) {
    int s = cl[j];
    ushort4 hv = *(const ushort4*)(H + (size_t)s * DHID + lane * 4);
    a0 += bf2f(hv.x); a1v += bf2f(hv.y);
    a2 += bf2f(hv.z); a3 += bf2f(hv.w);
  }
  float di = dv[node];
  float4 bb = *(const float4*)(b1 + lane * 4);
  a0 = fmaxf(fmaf(a0, di, bb.x), 0.f); a1v = fmaxf(fmaf(a1v, di, bb.y), 0.f);
  a2 = fmaxf(fmaf(a2, di, bb.z), 0.f); a3 = fmaxf(fmaf(a3, di, bb.w), 0.f);
  ushort4 out;
  out.x = f2bf(a0); out.y = f2bf(a1v); out.z = f2bf(a2); out.w = f2bf(a3);
  *(ushort4*)(O + (size_t)node * DHID + lane * 4) = out;
}

// D=128: lane covers 2 cols; fp32 output to d_out, scale+bias, no relu

__global__ __launch_bounds__(256) void agg2_kernel(
    const unsigned short* __restrict__ m2, float* __restrict__ out,
    const int* __restrict__ rowptr, const unsigned short* __restrict__ col,
    const float* __restrict__ dinv, const float* __restrict__ b2) {
  int g = blockIdx.y;
  const unsigned short* H = m2 + (size_t)g * NN * DHID;  // m2 in m1 buffer (graph stride NN*DHID, row stride DOUT)
  float* O = out + (size_t)g * NN * DOUT;
  const int* rp = rowptr + g * (NN + 1);
  const unsigned short* cl = col + (size_t)g * NE;
  const float* dv = dinv + g * NN;
  int node = blockIdx.x * 4 + (threadIdx.x >> 6);
  if (node >= NN) return;
  int lane = threadIdx.x & 63;
  ushort2 sv = *(const ushort2*)(H + (size_t)node * DOUT + lane * 2);
  float a0 = bf2f(sv.x), a1v = bf2f(sv.y);
  int jb = rp[node], je = rp[node + 1];
  int j = jb;
  for (; j + 16 <= je; j += 16) {
    int s[16];
    ushort2 v[16];
#pragma unroll
    for (int u = 0; u < 16; u++) s[u] = cl[j + u];
#pragma unroll
    for (int u = 0; u < 16; u++) v[u] = *(const ushort2*)(H + (size_t)s[u] * DOUT + lane * 2);
#pragma unroll
    for (int u = 0; u < 16; u++) { a0 += bf2f(v[u].x); a1v += bf2f(v[u].y); }
  }
  for (; j + 8 <= je; j += 8) {
    int s[8];
    ushort2 v[8];
#pragma unroll
    for (int u = 0; u < 8; u++) s[u] = cl[j + u];
#pragma unroll
    for (int u = 0; u < 8; u++) v[u] = *(const ushort2*)(H + (size_t)s[u] * DOUT + lane * 2);
#pragma unroll
    for (int u = 0; u < 8; u++) { a0 += bf2f(v[u].x); a1v += bf2f(v[u].y); }
  }
  for (; j < je; j++) {
    int s = cl[j];
    ushort2 hv = *(const ushort2*)(H + (size_t)s * DOUT + lane * 2);
    a0 += bf2f(hv.x); a1v += bf2f(hv.y);
  }
  float di = dv[node];
  float2 bb = *(const float2*)(b2 + lane * 2);
  float2 res;
  res.x = fmaf(a0, di, bb.x); res.y = fmaf(a1v, di, bb.y);
  *(float2*)(O + (size_t)node * DOUT + lane * 2) = res;
}

// ---------------- launch ----------------

extern "C" void kernel_launch(void* const* d_in, const int* in_sizes, int n_in,
                              void* d_out, int out_size, void* d_ws, size_t ws_size,
                              hipStream_t stream) {
  const float* x1 = (const float*)d_in[0];
  const int* e1 = (const int*)d_in[1];
  const float* x2 = (const float*)d_in[2];
  const int* e2 = (const int*)d_in[3];
  const float* W1 = (const float*)d_in[4];
  const float* b1 = (const float*)d_in[5];
  const float* W2 = (const float*)d_in[6];
  const float* b2 = (const float*)d_in[7];
  float* out = (float*)d_out;

  char* base = (char*)d_ws;
  size_t off = 0;
  auto alloc = [&](size_t bytes) -> void* {
    void* p = base + off;
    off = (off + bytes + 511) & ~(size_t)511;
    return p;
  };
  int* counts = (int*)alloc((size_t)2 * NN * 4);
  int* rowptr = (int*)alloc((size_t)2 * (NN + 1) * 4);
  int* cursor = (int*)alloc((size_t)2 * NN * 4);
  float* dinv = (float*)alloc((size_t)2 * NN * 4);
  unsigned short* col = (unsigned short*)alloc((size_t)2 * NE * 2);
  unsigned short* m1 = (unsigned short*)alloc((size_t)2 * NN * DHID * 2);  // also reused as m2
  unsigned short* a1 = (unsigned short*)alloc((size_t)2 * NN * DHID * 2);
  unsigned short* P1 = (unsigned short*)alloc((size_t)8 * 16 * 64 * 8 * 2);
  unsigned short* P2 = (unsigned short*)alloc((size_t)8 * 8 * 64 * 8 * 2);

  hipMemsetAsync(counts, 0, (size_t)2 * NN * 4, stream);
  hist_kernel<<<dim3((NE + 255) / 256, 2), 256, 0, stream>>>(e1, e2, counts);
  scan_kernel<<<2, 1024, 0, stream>>>(counts, rowptr, cursor, dinv);
  scatter_kernel<<<dim3((NE + 255) / 256, 2), 256, 0, stream>>>(e1, e2, cursor, col);
  pack_kernel<<<(98304 + 255) / 256, 256, 0, stream>>>(W1, W2, P1, P2);
  // layer 1: m1 = (x @ W1) * dinv (bf16), agg+scale+bias+relu -> a1
  mm_kernel<DHID, true><<<dim3((NN + 63) / 64, 2), 256, 0, stream>>>(
      x1, x2, P1, m1, dinv, (long long)NN * DHID);
  agg1_kernel<<<dim3(NN / 4, 2), 256, 0, stream>>>(m1, a1, rowptr, col, dinv, b1);
  // layer 2: m2 = (a1 @ W2) * dinv (into m1 buffer), agg+scale+bias -> d_out
  mm_kernel<DOUT, false><<<dim3((NN + 63) / 64, 2), 256, 0, stream>>>(
      a1, a1 + (size_t)NN * DHID, P2, m1, dinv, (long long)NN * DHID);
  agg2_kernel<<<dim3(NN / 4, 2), 256, 0, stream>>>(m1, out, rowptr, col, dinv, b2);
}

// Round 4
// 591.733 us; speedup vs baseline: 1.2669x; 1.2669x over previous
//
#include <hip/hip_runtime.h>

typedef __bf16 bf16x8 __attribute__((ext_vector_type(8)));
typedef float f32x4 __attribute__((ext_vector_type(4)));

constexpr int NN = 50000;   // nodes
constexpr int NE = 800000;  // edges
constexpr int DIN = 256, DHID = 256, DOUT = 128;
constexpr int NCH = (NN + 255) / 256;  // 196 chunks of 256

__device__ __forceinline__ unsigned short f2bf(float f) {
  unsigned u = __float_as_uint(f);
  u += 0x7fffu + ((u >> 16) & 1u);  // RNE
  return (unsigned short)(u >> 16);
}
__device__ __forceinline__ float bf2f(unsigned short h) {
  return __uint_as_float(((unsigned)h) << 16);
}

// ---------------- CSR build ----------------

__global__ void hist_kernel(const int* __restrict__ e0, const int* __restrict__ e1,
                            int* __restrict__ counts) {
  int g = blockIdx.y;
  const int* dst = (g ? e1 : e0) + NE;  // edge_index row 1
  int* c = counts + g * NN;
  int i = blockIdx.x * blockDim.x + threadIdx.x;
  if (i < NE) atomicAdd(&c[dst[i]], 1);
}

// 3-phase hierarchical exclusive scan of counts -> rowptr/cursor (+dinv)

// Phase A: per-chunk reduce (grid: NCH x 2)
__global__ __launch_bounds__(256) void scanA_kernel(const int* __restrict__ counts,
                                                    int* __restrict__ bsum) {
  int g = blockIdx.y, chunk = blockIdx.x, t = threadIdx.x;
  int i = chunk * 256 + t;
  int v = (i < NN) ? counts[g * NN + i] : 0;
  __shared__ int sh[256];
  sh[t] = v;
  __syncthreads();
  for (int off = 128; off > 0; off >>= 1) {
    if (t < off) sh[t] += sh[t + off];
    __syncthreads();
  }
  if (t == 0) bsum[g * NCH + chunk] = sh[0];
}

// Phase B: scan the NCH block sums (grid: 2), write exclusive bases in place
__global__ __launch_bounds__(256) void scanB_kernel(int* __restrict__ bsum,
                                                    int* __restrict__ rowptr) {
  int g = blockIdx.x, t = threadIdx.x;
  int v = (t < NCH) ? bsum[g * NCH + t] : 0;
  __shared__ int sh[256];
  sh[t] = v;
  __syncthreads();
  for (int off = 1; off < 256; off <<= 1) {
    int x = (t >= off) ? sh[t - off] : 0;
    __syncthreads();
    if (t >= off) sh[t] += x;
    __syncthreads();
  }
  if (t < NCH) bsum[g * NCH + t] = sh[t] - v;  // exclusive base
  if (t == 255) rowptr[g * (NN + 1) + NN] = sh[255];
}

// Phase C: block-local exclusive scan + base -> rowptr/cursor; dinv elementwise
__global__ __launch_bounds__(256) void scanC_kernel(const int* __restrict__ counts,
                                                    const int* __restrict__ bsum,
                                                    int* __restrict__ rowptr,
                                                    int* __restrict__ cursor,
                                                    float* __restrict__ dinv) {
  int g = blockIdx.y, chunk = blockIdx.x, t = threadIdx.x;
  int i = chunk * 256 + t;
  int v = (i < NN) ? counts[g * NN + i] : 0;
  __shared__ int sh[256];
  sh[t] = v;
  __syncthreads();
  for (int off = 1; off < 256; off <<= 1) {
    int x = (t >= off) ? sh[t - off] : 0;
    __syncthreads();
    if (t >= off) sh[t] += x;
    __syncthreads();
  }
  if (i < NN) {
    int run = bsum[g * NCH + chunk] + sh[t] - v;
    rowptr[g * (NN + 1) + i] = run;
    cursor[g * NN + i] = run;
    dinv[g * NN + i] = rsqrtf((float)(v + 1));  // +1 self-loop
  }
}

__global__ void scatter_kernel(const int* __restrict__ e0, const int* __restrict__ e1,
                               int* __restrict__ cursor, unsigned short* __restrict__ col) {
  int g = blockIdx.y;
  const int* e = g ? e1 : e0;
  int* cur = cursor + g * NN;
  unsigned short* cl = col + g * NE;
  int i = blockIdx.x * blockDim.x + threadIdx.x;
  if (i < NE) {
    int s = e[i], d = e[NE + i];
    int slot = atomicAdd(&cur[d], 1);
    cl[slot] = (unsigned short)s;
  }
}

// ---------------- Pack W into B-fragment order ----------------
// Wpack flat index: ((kb*NT + nt)*64 + lane)*8 + j  holds W[kb*32 + (lane>>4)*8 + j][nt*16 + (lane&15)]

__global__ void pack_kernel(const float* __restrict__ W1, const float* __restrict__ W2,
                            unsigned short* __restrict__ P1, unsigned short* __restrict__ P2) {
  int i = blockIdx.x * blockDim.x + threadIdx.x;
  constexpr int N1 = 8 * 16 * 64 * 8;  // 65536 (K=256, N=256)
  constexpr int N2 = 8 * 8 * 64 * 8;   // 32768 (K=256, N=128)
  if (i < N1) {
    int j = i & 7, lane = (i >> 3) & 63, grp = i >> 9;
    int nt = grp & 15, kb = grp >> 4;
    int k = kb * 32 + (lane >> 4) * 8 + j;
    int n = nt * 16 + (lane & 15);
    P1[i] = f2bf(W1[k * DHID + n]);
  } else if (i < N1 + N2) {
    int ii = i - N1;
    int j = ii & 7, lane = (ii >> 3) & 63, grp = ii >> 9;
    int nt = grp & 7, kb = grp >> 3;
    int k = kb * 32 + (lane >> 4) * 8 + j;
    int n = nt * 16 + (lane & 15);
    P2[ii] = f2bf(W2[k * DOUT + n]);
  }
}

// ---------------- MFMA matmul: C[M,N] = (A[M,256] @ W) * dinv[row] ----------------
// wave handles 16 rows x N cols; block = 4 waves = 64 rows.
// Rows are pre-scaled by dinv so aggregation is a plain sum (norm factored).

template <int N, bool AF32>
__global__ __launch_bounds__(256) void mm_kernel(
    const void* __restrict__ A0, const void* __restrict__ A1,
    const unsigned short* __restrict__ Wp, unsigned short* __restrict__ Cb,
    const float* __restrict__ dinv, long long gstride) {
  constexpr int NT = N / 16;
  constexpr int K = 256;
  int g = blockIdx.y;
  const void* A = g ? A1 : A0;
  unsigned short* C = Cb + (size_t)g * gstride;
  const float* dv = dinv + g * NN;
  int wave = threadIdx.x >> 6, lane = threadIdx.x & 63;
  int q = lane >> 4, lm = lane & 15;
  int m0 = blockIdx.x * 64 + wave * 16;
  int row = m0 + lm;
  int rowc = min(row, NN - 1);
  f32x4 acc[NT];
#pragma unroll
  for (int nt = 0; nt < NT; nt++) acc[nt] = (f32x4){0.f, 0.f, 0.f, 0.f};
#pragma unroll
  for (int kb = 0; kb < K / 32; kb++) {
    int kc = kb * 32 + q * 8;  // lane's contiguous k-chunk (A frag: k = quad*8+j)
    bf16x8 a;
    if constexpr (AF32) {
      const float* Af = (const float*)A + (size_t)rowc * K + kc;
      const float4 v0 = *(const float4*)Af;
      const float4 v1 = *(const float4*)(Af + 4);
      a[0] = (__bf16)v0.x; a[1] = (__bf16)v0.y; a[2] = (__bf16)v0.z; a[3] = (__bf16)v0.w;
      a[4] = (__bf16)v1.x; a[5] = (__bf16)v1.y; a[6] = (__bf16)v1.z; a[7] = (__bf16)v1.w;
    } else {
      const unsigned short* Ab = (const unsigned short*)A + (size_t)rowc * K + kc;
      a = *(const bf16x8*)Ab;
    }
#pragma unroll
    for (int nt = 0; nt < NT; nt++) {
      bf16x8 b = *(const bf16x8*)(Wp + (((size_t)kb * NT + nt) * 64 + lane) * 8);
      acc[nt] = __builtin_amdgcn_mfma_f32_16x16x32_bf16(a, b, acc[nt], 0, 0, 0);
    }
  }
  // C/D layout: col = lane&15, row = quad*4 + reg
  float dvr[4];
#pragma unroll
  for (int r = 0; r < 4; r++) dvr[r] = dv[min(m0 + q * 4 + r, NN - 1)];
#pragma unroll
  for (int nt = 0; nt < NT; nt++) {
#pragma unroll
    for (int r = 0; r < 4; r++) {
      int grow = m0 + q * 4 + r;
      if (grow < NN) C[(size_t)grow * N + nt * 16 + lm] = f2bf(acc[nt][r] * dvr[r]);
    }
  }
}

// ---------------- Aggregation (gather over CSR), fused scale+bias(+ReLU) ----------
// one wave per node; D=256: lane covers 4 cols. Rows pre-scaled by dinv[src], so
// inner loop is a pure gather-add; epilogue multiplies by dinv[node].
// Unroll 16/8/1 for memory-level parallelism.

__global__ __launch_bounds__(256) void agg1_kernel(
    const unsigned short* __restrict__ m1, unsigned short* __restrict__ a1,
    const int* __restrict__ rowptr, const unsigned short* __restrict__ col,
    const float* __restrict__ dinv, const float* __restrict__ b1) {
  int g = blockIdx.y;
  const unsigned short* H = m1 + (size_t)g * NN * DHID;
  unsigned short* O = a1 + (size_t)g * NN * DHID;
  const int* rp = rowptr + g * (NN + 1);
  const unsigned short* cl = col + (size_t)g * NE;
  const float* dv = dinv + g * NN;
  int node = blockIdx.x * 4 + (threadIdx.x >> 6);
  if (node >= NN) return;
  int lane = threadIdx.x & 63;
  ushort4 sv = *(const ushort4*)(H + (size_t)node * DHID + lane * 4);
  float a0 = bf2f(sv.x), a1v = bf2f(sv.y), a2 = bf2f(sv.z), a3 = bf2f(sv.w);
  int jb = rp[node], je = rp[node + 1];
  int j = jb;
  for (; j + 16 <= je; j += 16) {
    int s[16];
    ushort4 v[16];
#pragma unroll
    for (int u = 0; u < 16; u++) s[u] = cl[j + u];
#pragma unroll
    for (int u = 0; u < 16; u++) v[u] = *(const ushort4*)(H + (size_t)s[u] * DHID + lane * 4);
#pragma unroll
    for (int u = 0; u < 16; u++) {
      a0 += bf2f(v[u].x); a1v += bf2f(v[u].y);
      a2 += bf2f(v[u].z); a3 += bf2f(v[u].w);
    }
  }
  for (; j + 8 <= je; j += 8) {
    int s[8];
    ushort4 v[8];
#pragma unroll
    for (int u = 0; u < 8; u++) s[u] = cl[j + u];
#pragma unroll
    for (int u = 0; u < 8; u++) v[u] = *(const ushort4*)(H + (size_t)s[u] * DHID + lane * 4);
#pragma unroll
    for (int u = 0; u < 8; u++) {
      a0 += bf2f(v[u].x); a1v += bf2f(v[u].y);
      a2 += bf2f(v[u].z); a3 += bf2f(v[u].w);
    }
  }
  for (; j < je; j++) {
    int s = cl[j];
    ushort4 hv = *(const ushort4*)(H + (size_t)s * DHID + lane * 4);
    a0 += bf2f(hv.x); a1v += bf2f(hv.y);
    a2 += bf2f(hv.z); a3 += bf2f(hv.w);
  }
  float di = dv[node];
  float4 bb = *(const float4*)(b1 + lane * 4);
  a0 = fmaxf(fmaf(a0, di, bb.x), 0.f); a1v = fmaxf(fmaf(a1v, di, bb.y), 0.f);
  a2 = fmaxf(fmaf(a2, di, bb.z), 0.f); a3 = fmaxf(fmaf(a3, di, bb.w), 0.f);
  ushort4 out;
  out.x = f2bf(a0); out.y = f2bf(a1v); out.z = f2bf(a2); out.w = f2bf(a3);
  *(ushort4*)(O + (size_t)node * DHID + lane * 4) = out;
}

// D=128: lane covers 2 cols; fp32 output to d_out, scale+bias, no relu

__global__ __launch_bounds__(256) void agg2_kernel(
    const unsigned short* __restrict__ m2, float* __restrict__ out,
    const int* __restrict__ rowptr, const unsigned short* __restrict__ col,
    const float* __restrict__ dinv, const float* __restrict__ b2) {
  int g = blockIdx.y;
  const unsigned short* H = m2 + (size_t)g * NN * DHID;  // m2 in m1 buffer (graph stride NN*DHID, row stride DOUT)
  float* O = out + (size_t)g * NN * DOUT;
  const int* rp = rowptr + g * (NN + 1);
  const unsigned short* cl = col + (size_t)g * NE;
  const float* dv = dinv + g * NN;
  int node = blockIdx.x * 4 + (threadIdx.x >> 6);
  if (node >= NN) return;
  int lane = threadIdx.x & 63;
  ushort2 sv = *(const ushort2*)(H + (size_t)node * DOUT + lane * 2);
  float a0 = bf2f(sv.x), a1v = bf2f(sv.y);
  int jb = rp[node], je = rp[node + 1];
  int j = jb;
  for (; j + 16 <= je; j += 16) {
    int s[16];
    ushort2 v[16];
#pragma unroll
    for (int u = 0; u < 16; u++) s[u] = cl[j + u];
#pragma unroll
    for (int u = 0; u < 16; u++) v[u] = *(const ushort2*)(H + (size_t)s[u] * DOUT + lane * 2);
#pragma unroll
    for (int u = 0; u < 16; u++) { a0 += bf2f(v[u].x); a1v += bf2f(v[u].y); }
  }
  for (; j + 8 <= je; j += 8) {
    int s[8];
    ushort2 v[8];
#pragma unroll
    for (int u = 0; u < 8; u++) s[u] = cl[j + u];
#pragma unroll
    for (int u = 0; u < 8; u++) v[u] = *(const ushort2*)(H + (size_t)s[u] * DOUT + lane * 2);
#pragma unroll
    for (int u = 0; u < 8; u++) { a0 += bf2f(v[u].x); a1v += bf2f(v[u].y); }
  }
  for (; j < je; j++) {
    int s = cl[j];
    ushort2 hv = *(const ushort2*)(H + (size_t)s * DOUT + lane * 2);
    a0 += bf2f(hv.x); a1v += bf2f(hv.y);
  }
  float di = dv[node];
  float2 bb = *(const float2*)(b2 + lane * 2);
  float2 res;
  res.x = fmaf(a0, di, bb.x); res.y = fmaf(a1v, di, bb.y);
  *(float2*)(O + (size_t)node * DOUT + lane * 2) = res;
}

// ---------------- launch ----------------

extern "C" void kernel_launch(void* const* d_in, const int* in_sizes, int n_in,
                              void* d_out, int out_size, void* d_ws, size_t ws_size,
                              hipStream_t stream) {
  const float* x1 = (const float*)d_in[0];
  const int* e1 = (const int*)d_in[1];
  const float* x2 = (const float*)d_in[2];
  const int* e2 = (const int*)d_in[3];
  const float* W1 = (const float*)d_in[4];
  const float* b1 = (const float*)d_in[5];
  const float* W2 = (const float*)d_in[6];
  const float* b2 = (const float*)d_in[7];
  float* out = (float*)d_out;

  char* base = (char*)d_ws;
  size_t off = 0;
  auto alloc = [&](size_t bytes) -> void* {
    void* p = base + off;
    off = (off + bytes + 511) & ~(size_t)511;
    return p;
  };
  int* counts = (int*)alloc((size_t)2 * NN * 4);
  int* rowptr = (int*)alloc((size_t)2 * (NN + 1) * 4);
  int* cursor = (int*)alloc((size_t)2 * NN * 4);
  float* dinv = (float*)alloc((size_t)2 * NN * 4);
  int* bsum = (int*)alloc((size_t)2 * NCH * 4);
  unsigned short* col = (unsigned short*)alloc((size_t)2 * NE * 2);
  unsigned short* m1 = (unsigned short*)alloc((size_t)2 * NN * DHID * 2);  // also reused as m2
  unsigned short* a1 = (unsigned short*)alloc((size_t)2 * NN * DHID * 2);
  unsigned short* P1 = (unsigned short*)alloc((size_t)8 * 16 * 64 * 8 * 2);
  unsigned short* P2 = (unsigned short*)alloc((size_t)8 * 8 * 64 * 8 * 2);

  hipMemsetAsync(counts, 0, (size_t)2 * NN * 4, stream);
  hist_kernel<<<dim3((NE + 255) / 256, 2), 256, 0, stream>>>(e1, e2, counts);
  scanA_kernel<<<dim3(NCH, 2), 256, 0, stream>>>(counts, bsum);
  scanB_kernel<<<2, 256, 0, stream>>>(bsum, rowptr);
  scanC_kernel<<<dim3(NCH, 2), 256, 0, stream>>>(counts, bsum, rowptr, cursor, dinv);
  scatter_kernel<<<dim3((NE + 255) / 256, 2), 256, 0, stream>>>(e1, e2, cursor, col);
  pack_kernel<<<(98304 + 255) / 256, 256, 0, stream>>>(W1, W2, P1, P2);
  // layer 1: m1 = (x @ W1) * dinv (bf16), agg+scale+bias+relu -> a1
  mm_kernel<DHID, true><<<dim3((NN + 63) / 64, 2), 256, 0, stream>>>(
      x1, x2, P1, m1, dinv, (long long)NN * DHID);
  agg1_kernel<<<dim3(NN / 4, 2), 256, 0, stream>>>(m1, a1, rowptr, col, dinv, b1);
  // layer 2: m2 = (a1 @ W2) * dinv (into m1 buffer), agg+scale+bias -> d_out
  mm_kernel<DOUT, false><<<dim3((NN + 63) / 64, 2), 256, 0, stream>>>(
      a1, a1 + (size_t)NN * DHID, P2, m1, dinv, (long long)NN * DHID);
  agg2_kernel<<<dim3(NN / 4, 2), 256, 0, stream>>>(m1, out, rowptr, col, dinv, b2);
}